// Round 1
// baseline (107.279 us; speedup 1.0000x reference)
//
#include <hip/hip_runtime.h>

// knnLoss: B=4 batches, downsample 400x400 stride-4 -> 10000 points of 3 ch,
// nearest-neighbor squared distance mean.
//
// d2(t,s) = tt + ss - 2*t.s ; per target we min over (ss - 2*t.s) and add tt
// at the end. Sources pre-transformed to float4(-2x,-2y,-2z,ss) so the inner
// loop is 3 fma + 1 min per pair.

#define BATCH  4
#define NPTS   10000
#define NPAD   10240      // padded target count per batch (multiple of 1024)
#define H      400
#define W      400
#define STRIDE 4
#define OUTW   100
#define NC     16         // source chunks
#define CHUNK  625        // NPTS / NC
#define TBLKS  10         // target blocks per batch (NPAD / (BLOCK*TPT))
#define BLOCK  256
#define TPT    4          // targets per thread

// ---------------------------------------------------------------- kernel 1
// Downsample + transform. gid < BATCH*NPAD -> targets (pad with zeros),
// else sources.
__global__ void prep_kernel(const float* __restrict__ tgt,
                            const float* __restrict__ src,
                            float4* __restrict__ S4,
                            float4* __restrict__ T4) {
    int gid = blockIdx.x * blockDim.x + threadIdx.x;
    if (gid < BATCH * NPAD) {
        int b = gid / NPAD;
        int n = gid % NPAD;
        float4 v = make_float4(0.f, 0.f, 0.f, 0.f);
        if (n < NPTS) {
            int h = n / OUTW, w = n % OUTW;
            int base = ((b * 3) * H + h * STRIDE) * W + w * STRIDE;
            float x = tgt[base];
            float y = tgt[base + H * W];
            float z = tgt[base + 2 * H * W];
            v = make_float4(x, y, z, x * x + y * y + z * z);
        }
        T4[gid] = v;
    } else {
        int sid = gid - BATCH * NPAD;
        if (sid < BATCH * NPTS) {
            int b = sid / NPTS;
            int m = sid % NPTS;
            int h = m / OUTW, w = m % OUTW;
            int base = ((b * 3) * H + h * STRIDE) * W + w * STRIDE;
            float x = src[base];
            float y = src[base + H * W];
            float z = src[base + 2 * H * W];
            S4[sid] = make_float4(-2.f * x, -2.f * y, -2.f * z,
                                  x * x + y * y + z * z);
        }
    }
}

// ---------------------------------------------------------------- kernel 2
// Each block: one (batch, target-block of 1024, source-chunk of 625).
// Stage chunk in LDS; each thread holds 4 targets in regs.
// Writes per-chunk partial min of (ss - 2*t.s) to M2[chunk][b][npad].
__global__ __launch_bounds__(BLOCK) void knn_kernel(
        const float4* __restrict__ S4,
        const float4* __restrict__ T4,
        float* __restrict__ M2) {
    __shared__ float4 lds[CHUNK];
    const int tblk = blockIdx.x;  // 0..TBLKS-1
    const int cblk = blockIdx.y;  // 0..NC-1
    const int b    = blockIdx.z;  // 0..BATCH-1
    const int tid  = threadIdx.x;

    const float4* sbase = S4 + b * NPTS + cblk * CHUNK;
    for (int i = tid; i < CHUNK; i += BLOCK) lds[i] = sbase[i];

    const int tbase = b * NPAD + tblk * (BLOCK * TPT) + tid;
    float tx[TPT], ty[TPT], tz[TPT], mn[TPT];
#pragma unroll
    for (int k = 0; k < TPT; k++) {
        float4 t = T4[tbase + k * BLOCK];
        tx[k] = t.x; ty[k] = t.y; tz[k] = t.z;
        mn[k] = 3.0e38f;
    }
    __syncthreads();

#pragma unroll 5
    for (int j = 0; j < CHUNK; j++) {
        float4 s = lds[j];           // ds_read_b128, wave-uniform broadcast
#pragma unroll
        for (int k = 0; k < TPT; k++) {
            float d = fmaf(tx[k], s.x, s.w);
            d = fmaf(ty[k], s.y, d);
            d = fmaf(tz[k], s.z, d);
            mn[k] = fminf(mn[k], d);
        }
    }

    float* obase = M2 + (cblk * BATCH + b) * NPAD + tblk * (BLOCK * TPT) + tid;
#pragma unroll
    for (int k = 0; k < TPT; k++) obase[k * BLOCK] = mn[k];
}

// ---------------------------------------------------------------- kernel 3
// Min across chunks, add tt, clamp >=0, sum -> scalar mean.
__global__ void reduce_kernel(const float* __restrict__ M2,
                              const float4* __restrict__ T4,
                              float* __restrict__ out) {
    __shared__ float red[BLOCK / 64];
    int gid = blockIdx.x * BLOCK + threadIdx.x;
    float val = 0.f;
    if (gid < BATCH * NPTS) {
        int b = gid / NPTS;
        int n = gid % NPTS;
        float m = 3.0e38f;
#pragma unroll
        for (int c = 0; c < NC; c++)
            m = fminf(m, M2[(c * BATCH + b) * NPAD + n]);
        float tt = T4[b * NPAD + n].w;
        val = fmaxf(m + tt, 0.f);
    }
#pragma unroll
    for (int off = 32; off > 0; off >>= 1)
        val += __shfl_down(val, off, 64);
    int lane = threadIdx.x & 63;
    int wave = threadIdx.x >> 6;
    if (lane == 0) red[wave] = val;
    __syncthreads();
    if (threadIdx.x == 0) {
        float s = 0.f;
        for (int wv = 0; wv < BLOCK / 64; wv++) s += red[wv];
        atomicAdd(out, s * (1.0f / (BATCH * NPTS * 3)));
    }
}

extern "C" void kernel_launch(void* const* d_in, const int* in_sizes, int n_in,
                              void* d_out, int out_size, void* d_ws, size_t ws_size,
                              hipStream_t stream) {
    const float* tgt = (const float*)d_in[0];   // target_pc (4,3,400,400)
    const float* src = (const float*)d_in[1];   // source_pc (4,3,400,400)
    float* out = (float*)d_out;

    char* ws = (char*)d_ws;
    float4* S4 = (float4*)ws;                                   // B*NPTS float4
    float4* T4 = (float4*)(ws + (size_t)BATCH * NPTS * 16);     // B*NPAD float4
    float*  M2 = (float*)(ws + (size_t)BATCH * NPTS * 16
                             + (size_t)BATCH * NPAD * 16);      // NC*B*NPAD floats

    hipMemsetAsync(out, 0, sizeof(float), stream);

    int nprep = BATCH * NPAD + BATCH * NPTS;
    prep_kernel<<<(nprep + 255) / 256, 256, 0, stream>>>(tgt, src, S4, T4);

    knn_kernel<<<dim3(TBLKS, NC, BATCH), BLOCK, 0, stream>>>(S4, T4, M2);

    reduce_kernel<<<(BATCH * NPTS + BLOCK - 1) / BLOCK, BLOCK, 0, stream>>>(
        M2, T4, out);
}

// Round 2
// 102.520 us; speedup vs baseline: 1.0464x; 1.0464x over previous
//
#include <hip/hip_runtime.h>

// knnLoss: B=4, downsample 400x400 stride-4 -> 10000 pts x 3ch, NN sq-dist mean.
// d2(t,s) = tt + (ss - 2 t.s); min over the paren term, add tt at the end.
// Sources pre-transformed to float4(-2x,-2y,-2z,ss): inner pair = 3 fma,
// min-reduction via v_min3_f32 trees = 0.5 instr/pair -> 3.5 VALU/pair.

#define BATCH  4
#define NPTS   10000
#define NPAD   10240      // padded target count per batch
#define H      400
#define W      400
#define STRIDE 4
#define OUTW   100
#define NC     16         // source chunks
#define CHUNK  625        // NPTS / NC
#define CPAD   628        // chunk padded to multiple of 4 with sentinels
#define BLOCK  256
#define TPT    2          // targets per thread
#define TBLKS  20         // NPAD / (BLOCK*TPT) -> grid 20*16*4 = 1280 = 5/CU even

__device__ __forceinline__ float min3f(float a, float b, float c) {
    float r;
    asm("v_min3_f32 %0, %1, %2, %3" : "=v"(r) : "v"(a), "v"(b), "v"(c));
    return r;
}

// ---------------------------------------------------------------- kernel 1
__global__ void prep_kernel(const float* __restrict__ tgt,
                            const float* __restrict__ src,
                            float4* __restrict__ S4,
                            float4* __restrict__ T4) {
    int gid = blockIdx.x * blockDim.x + threadIdx.x;
    if (gid < BATCH * NPAD) {
        int b = gid / NPAD;
        int n = gid % NPAD;
        float4 v = make_float4(0.f, 0.f, 0.f, 0.f);
        if (n < NPTS) {
            int h = n / OUTW, w = n % OUTW;
            int base = ((b * 3) * H + h * STRIDE) * W + w * STRIDE;
            float x = tgt[base];
            float y = tgt[base + H * W];
            float z = tgt[base + 2 * H * W];
            v = make_float4(x, y, z, x * x + y * y + z * z);
        }
        T4[gid] = v;
    } else {
        int sid = gid - BATCH * NPAD;
        if (sid < BATCH * NPTS) {
            int b = sid / NPTS;
            int m = sid % NPTS;
            int h = m / OUTW, w = m % OUTW;
            int base = ((b * 3) * H + h * STRIDE) * W + w * STRIDE;
            float x = src[base];
            float y = src[base + H * W];
            float z = src[base + 2 * H * W];
            S4[sid] = make_float4(-2.f * x, -2.f * y, -2.f * z,
                                  x * x + y * y + z * z);
        }
    }
}

// ---------------------------------------------------------------- kernel 2
// block = (tblk, cblk, b): 512 targets x 625-source chunk.
// Each thread: 2 targets in regs, running min of (ss - 2 t.s).
__global__ __launch_bounds__(BLOCK) void knn_kernel(
        const float4* __restrict__ S4,
        const float4* __restrict__ T4,
        float* __restrict__ M2) {
    __shared__ float4 lds[CPAD];
    const int tblk = blockIdx.x;  // 0..TBLKS-1
    const int cblk = blockIdx.y;  // 0..NC-1
    const int b    = blockIdx.z;  // 0..BATCH-1
    const int tid  = threadIdx.x;

    const float4* sbase = S4 + b * NPTS + cblk * CHUNK;
    for (int i = tid; i < CHUNK; i += BLOCK) lds[i] = sbase[i];
    if (tid < CPAD - CHUNK) lds[CHUNK + tid] = make_float4(0.f, 0.f, 0.f, 3.0e38f);

    const int tbase = b * NPAD + tblk * (BLOCK * TPT) + tid;
    float tx[TPT], ty[TPT], tz[TPT], mn[TPT];
#pragma unroll
    for (int k = 0; k < TPT; k++) {
        float4 t = T4[tbase + k * BLOCK];
        tx[k] = t.x; ty[k] = t.y; tz[k] = t.z;
        mn[k] = 3.0e38f;
    }
    __syncthreads();

#pragma unroll 2
    for (int j = 0; j < CPAD; j += 4) {
        float4 s0 = lds[j + 0];      // broadcast ds_read_b128 x4, independent
        float4 s1 = lds[j + 1];
        float4 s2 = lds[j + 2];
        float4 s3 = lds[j + 3];
#pragma unroll
        for (int k = 0; k < TPT; k++) {
            float d0 = fmaf(tx[k], s0.x, s0.w);
            d0 = fmaf(ty[k], s0.y, d0);
            d0 = fmaf(tz[k], s0.z, d0);
            float d1 = fmaf(tx[k], s1.x, s1.w);
            d1 = fmaf(ty[k], s1.y, d1);
            d1 = fmaf(tz[k], s1.z, d1);
            float d2 = fmaf(tx[k], s2.x, s2.w);
            d2 = fmaf(ty[k], s2.y, d2);
            d2 = fmaf(tz[k], s2.z, d2);
            float d3 = fmaf(tx[k], s3.x, s3.w);
            d3 = fmaf(ty[k], s3.y, d3);
            d3 = fmaf(tz[k], s3.z, d3);
            mn[k] = min3f(mn[k], min3f(d0, d1, d2), d3);
        }
    }

    float* obase = M2 + (cblk * BATCH + b) * NPAD + tblk * (BLOCK * TPT) + tid;
#pragma unroll
    for (int k = 0; k < TPT; k++) obase[k * BLOCK] = mn[k];
}

// ---------------------------------------------------------------- kernel 3
__global__ void reduce_kernel(const float* __restrict__ M2,
                              const float4* __restrict__ T4,
                              float* __restrict__ out) {
    __shared__ float red[BLOCK / 64];
    int gid = blockIdx.x * BLOCK + threadIdx.x;
    float val = 0.f;
    if (gid < BATCH * NPTS) {
        int b = gid / NPTS;
        int n = gid % NPTS;
        float m = 3.0e38f;
#pragma unroll
        for (int c = 0; c < NC; c++)
            m = fminf(m, M2[(c * BATCH + b) * NPAD + n]);
        float tt = T4[b * NPAD + n].w;
        val = fmaxf(m + tt, 0.f);
    }
#pragma unroll
    for (int off = 32; off > 0; off >>= 1)
        val += __shfl_down(val, off, 64);
    int lane = threadIdx.x & 63;
    int wave = threadIdx.x >> 6;
    if (lane == 0) red[wave] = val;
    __syncthreads();
    if (threadIdx.x == 0) {
        float s = 0.f;
        for (int wv = 0; wv < BLOCK / 64; wv++) s += red[wv];
        atomicAdd(out, s * (1.0f / (BATCH * NPTS * 3)));
    }
}

extern "C" void kernel_launch(void* const* d_in, const int* in_sizes, int n_in,
                              void* d_out, int out_size, void* d_ws, size_t ws_size,
                              hipStream_t stream) {
    const float* tgt = (const float*)d_in[0];   // target_pc (4,3,400,400)
    const float* src = (const float*)d_in[1];   // source_pc (4,3,400,400)
    float* out = (float*)d_out;

    char* ws = (char*)d_ws;
    float4* S4 = (float4*)ws;                                   // B*NPTS float4
    float4* T4 = (float4*)(ws + (size_t)BATCH * NPTS * 16);     // B*NPAD float4
    float*  M2 = (float*)(ws + (size_t)BATCH * NPTS * 16
                             + (size_t)BATCH * NPAD * 16);      // NC*B*NPAD floats

    hipMemsetAsync(out, 0, sizeof(float), stream);

    int nprep = BATCH * NPAD + BATCH * NPTS;
    prep_kernel<<<(nprep + 255) / 256, 256, 0, stream>>>(tgt, src, S4, T4);

    knn_kernel<<<dim3(TBLKS, NC, BATCH), BLOCK, 0, stream>>>(S4, T4, M2);

    reduce_kernel<<<(BATCH * NPTS + BLOCK - 1) / BLOCK, BLOCK, 0, stream>>>(
        M2, T4, out);
}